// Round 1
// baseline (1602.701 us; speedup 1.0000x reference)
//
#include <hip/hip_runtime.h>
#include <hip/hip_bf16.h>
#include <math.h>

// ---------------- problem constants ----------------
#define NB   256      // batch
#define NT   288      // total timesteps
#define NOBS 256
#define NTP  32

// output offsets (floats)
#define O_ST_OBS   0
#define O_ST_PRED  131072
#define O_ZM_OBS   147456
#define O_ZS_OBS   1196032
#define O_ZM_PRED  2244608
#define O_ZS_PRED  2375680
#define O_XREC     2506752
#define O_NLL      4079616

__device__ __forceinline__ float wred(float v) {
    v += __shfl_down(v, 32); v += __shfl_down(v, 16); v += __shfl_down(v, 8);
    v += __shfl_down(v, 4);  v += __shfl_down(v, 2);  v += __shfl_down(v, 1);
    return v;
}
__device__ __forceinline__ float sigm(float x) { return 1.0f / (1.0f + __expf(-x)); }
__device__ __forceinline__ float tanh_f(float x) {
    x = fminf(fmaxf(x, -15.0f), 15.0f);
    float e = __expf(2.0f * x);
    return (e - 1.0f) / (e + 1.0f);
}

// ==================== Kernel 1: encoder (blocks 0..287) + recurrence (block 288) ====================
extern "C" __global__ void __launch_bounds__(256)
k_enc_rec(const float* __restrict__ x,    const float* __restrict__ act,
          const int*   __restrict__ pos,  const float* __restrict__ s0,
          const float* __restrict__ nobs, const float* __restrict__ npred,
          const float* __restrict__ Wa,   const float* __restrict__ Ws1,
          const float* __restrict__ bs1,  const float* __restrict__ Ws2,
          const float* __restrict__ bs2,
          const float* __restrict__ Wc1,  const float* __restrict__ bc1,
          const float* __restrict__ g1,   const float* __restrict__ be1,
          const float* __restrict__ Wc2,  const float* __restrict__ bc2,
          const float* __restrict__ g2,   const float* __restrict__ be2,
          const float* __restrict__ Wzm,  const float* __restrict__ bzm,
          const float* __restrict__ Wzs,  const float* __restrict__ bzs,
          float* __restrict__ out)
{
    const int tid = threadIdx.x;

    if (blockIdx.x == 288) {
        // ---------------- state recurrence: thread = batch element ----------------
        const int b = tid;
        float wa[10], w1[10], w2[10], c1[5], c2[2];
#pragma unroll
        for (int i = 0; i < 10; i++) { wa[i] = Wa[i]; w1[i] = Ws1[i]; w2[i] = Ws2[i]; }
#pragma unroll
        for (int i = 0; i < 5; i++) c1[i] = bs1[i];
        c2[0] = bs2[0]; c2[1] = bs2[1];

        float sv0 = s0[b * 2 + 0], sv1 = s0[b * 2 + 1];
        out[O_ST_OBS + b * 2 + 0] = sv0;
        out[O_ST_OBS + b * 2 + 1] = sv1;
        if (b == 0) out[O_NLL] = 0.0f;   // re-zero every call (stream-ordered before k_dec)

        for (int t = 1; t < 288; t++) {
            float u0 = 0.f, u1 = 0.f;
#pragma unroll
            for (int a = 0; a < 5; a++) {
                const float av = act[(b * 5 + a) * 288 + t];
                u0 = fmaf(av, wa[a], u0);
                u1 = fmaf(av, wa[5 + a], u1);
            }
            const float v0 = sv0 + u0, v1 = sv1 + u1;
            float a0 = c2[0], a1 = c2[1];
#pragma unroll
            for (int j = 0; j < 5; j++) {
                const float hj = tanh_f(fmaf(v1, w1[j * 2 + 1], fmaf(v0, w1[j * 2 + 0], c1[j])));
                a0 = fmaf(hj, w2[j], a0);
                a1 = fmaf(hj, w2[5 + j], a1);
            }
            const float o0 = sigm(a0), o1 = sigm(a1);
            float n0, n1;
            if (t < 256) { n0 = nobs[((t - 1) * 256 + b) * 2 + 0];  n1 = nobs[((t - 1) * 256 + b) * 2 + 1]; }
            else         { n0 = npred[((t - 256) * 256 + b) * 2 + 0]; n1 = npred[((t - 256) * 256 + b) * 2 + 1]; }
            sv0 = fmaf(u0, o0, sv0) + n0;
            sv1 = fmaf(u1, o1, sv1) + n1;
            if (t < 256) {
                out[O_ST_OBS + (t * 256 + b) * 2 + 0] = sv0;
                out[O_ST_OBS + (t * 256 + b) * 2 + 1] = sv1;
            } else {
                out[O_ST_PRED + ((t - 256) * 256 + b) * 2 + 0] = sv0;
                out[O_ST_PRED + ((t - 256) * 256 + b) * 2 + 1] = sv1;
            }
        }
        return;
    }

    // ---------------- glimpse encoder for t = blockIdx.x, thread = batch element ----------------
    const int t = blockIdx.x;
    __shared__ __align__(16) float sWc1[192];
    __shared__ __align__(16) float sWc2[2048];
    __shared__ __align__(16) float sWzm[512];
    __shared__ __align__(16) float sWzs[512];
    __shared__ float sB1[16], sE1[16], sB2[32], sE2[32], sBzm[16], sBzs[16];
    __shared__ float sRed[4][64];
    __shared__ float sM1[16], sS1[16], sM2[32], sS2[32];

    for (int i = tid; i < 192; i += 256) sWc1[i] = Wc1[i];
    for (int i = tid; i < 2048; i += 256) sWc2[i] = Wc2[i];
    for (int i = tid; i < 512; i += 256) { sWzm[i] = Wzm[i]; sWzs[i] = Wzs[i]; }
    if (tid < 16) { sB1[tid] = bc1[tid]; sE1[tid] = be1[tid]; sBzm[tid] = bzm[tid]; sBzs[tid] = bzs[tid]; }
    if (tid < 32) { sB2[tid] = bc2[tid]; sE2[tid] = be2[tid]; }
    __syncthreads();

    const int b = tid;
    const int wid = tid >> 6, lane = tid & 63;
    const float* xb = x + b * 3072;
    const int pr = 3 * pos[(b * 2 + 0) * 288 + t];
    const int pc = 3 * pos[(b * 2 + 1) * 288 + t];

    // conv1 (3->16, 2x2, s2) + relu + maxpool 2x2 -> pooled[16][2][2]
    float pooled[64];
#pragma unroll
    for (int i = 0; i < 64; i++) pooled[i] = 0.f;   // relu outputs >= 0, so 0-init == true max

#pragma unroll
    for (int py = 0; py < 2; py++)
#pragma unroll
    for (int px = 0; px < 2; px++) {
#pragma unroll 1
        for (int d = 0; d < 4; d++) {
            const int dy = d >> 1, dx = d & 1;
            const int rbase = pr + 4 * py + 2 * dy;
            const int cbase = pc + 4 * px + 2 * dx;
            float in[12];
#pragma unroll
            for (int ic = 0; ic < 3; ic++)
#pragma unroll
            for (int ky = 0; ky < 2; ky++)
#pragma unroll
            for (int kx = 0; kx < 2; kx++)
                in[ic * 4 + ky * 2 + kx] = xb[ic * 1024 + (rbase + ky) * 32 + (cbase + kx)];
#pragma unroll
            for (int oc = 0; oc < 16; oc++) {
                float v = sB1[oc];
#pragma unroll
                for (int q = 0; q < 12; q++) v = fmaf(in[q], sWc1[oc * 12 + q], v);
                v = fmaxf(v, 0.f);
                pooled[oc * 4 + py * 2 + px] = fmaxf(pooled[oc * 4 + py * 2 + px], v);
            }
        }
    }

    // BN1: per-channel stats over (b, 2x2) => N = 1024
#pragma unroll
    for (int oc = 0; oc < 16; oc++) {
        float s = 0.f, ss = 0.f;
#pragma unroll
        for (int q = 0; q < 4; q++) { const float v = pooled[oc * 4 + q]; s += v; ss = fmaf(v, v, ss); }
        s = wred(s); ss = wred(ss);
        if (lane == 0) { sRed[wid][oc * 2] = s; sRed[wid][oc * 2 + 1] = ss; }
    }
    __syncthreads();
    if (tid < 16) {
        const float s  = sRed[0][tid * 2] + sRed[1][tid * 2] + sRed[2][tid * 2] + sRed[3][tid * 2];
        const float ss = sRed[0][tid * 2 + 1] + sRed[1][tid * 2 + 1] + sRed[2][tid * 2 + 1] + sRed[3][tid * 2 + 1];
        const float m = s * (1.f / 1024.f);
        const float var = fmaf(-m, m, ss * (1.f / 1024.f));
        sM1[tid] = m; sS1[tid] = g1[tid] * rsqrtf(var + 1e-5f);
    }
    __syncthreads();
#pragma unroll
    for (int oc = 0; oc < 16; oc++) {
        const float m = sM1[oc], sc = sS1[oc], e = sE1[oc];
#pragma unroll
        for (int q = 0; q < 4; q++) pooled[oc * 4 + q] = fmaf(pooled[oc * 4 + q] - m, sc, e);
    }

    // conv2 (16->32, 2x2 over the 2x2 input) + relu
    float h2v[32];
#pragma unroll
    for (int oc = 0; oc < 32; oc++) {
        float v = sB2[oc];
#pragma unroll
        for (int ic = 0; ic < 16; ic++) {
            const float4 w = *reinterpret_cast<const float4*>(&sWc2[oc * 64 + ic * 4]);
            v = fmaf(pooled[ic * 4 + 0], w.x, v); v = fmaf(pooled[ic * 4 + 1], w.y, v);
            v = fmaf(pooled[ic * 4 + 2], w.z, v); v = fmaf(pooled[ic * 4 + 3], w.w, v);
        }
        h2v[oc] = fmaxf(v, 0.f);
    }

    // BN2: per-channel over b => N = 256
#pragma unroll
    for (int oc = 0; oc < 32; oc++) {
        float s = wred(h2v[oc]), ss = wred(h2v[oc] * h2v[oc]);
        if (lane == 0) { sRed[wid][oc * 2] = s; sRed[wid][oc * 2 + 1] = ss; }
    }
    __syncthreads();
    if (tid < 32) {
        const float s  = sRed[0][tid * 2] + sRed[1][tid * 2] + sRed[2][tid * 2] + sRed[3][tid * 2];
        const float ss = sRed[0][tid * 2 + 1] + sRed[1][tid * 2 + 1] + sRed[2][tid * 2 + 1] + sRed[3][tid * 2 + 1];
        const float m = s * (1.f / 256.f);
        const float var = fmaf(-m, m, ss * (1.f / 256.f));
        sM2[tid] = m; sS2[tid] = g2[tid] * rsqrtf(var + 1e-5f);
    }
    __syncthreads();
#pragma unroll
    for (int oc = 0; oc < 32; oc++) h2v[oc] = fmaf(h2v[oc] - sM2[oc], sS2[oc], sE2[oc]);

    // zm / zs heads (32 -> 16 each)
    const int obase_m = (t < 256) ? (O_ZM_OBS + (t * 256 + b) * 16) : (O_ZM_PRED + ((t - 256) * 256 + b) * 16);
    const int obase_s = (t < 256) ? (O_ZS_OBS + (t * 256 + b) * 16) : (O_ZS_PRED + ((t - 256) * 256 + b) * 16);
#pragma unroll
    for (int k = 0; k < 16; k++) {
        float vm = sBzm[k], vs = sBzs[k];
#pragma unroll
        for (int c = 0; c < 32; c += 4) {
            const float4 wm = *reinterpret_cast<const float4*>(&sWzm[k * 32 + c]);
            const float4 ws4 = *reinterpret_cast<const float4*>(&sWzs[k * 32 + c]);
            vm = fmaf(h2v[c], wm.x, fmaf(h2v[c + 1], wm.y, fmaf(h2v[c + 2], wm.z, fmaf(h2v[c + 3], wm.w, vm))));
            vs = fmaf(h2v[c], ws4.x, fmaf(h2v[c + 1], ws4.y, fmaf(h2v[c + 2], ws4.z, fmaf(h2v[c + 3], ws4.w, vs))));
        }
        out[obase_m + k] = vm;
        out[obase_s + k] = __expf(vs);
    }
}

// ==================== Kernel 2: decoder + nll (block = pred timestep) ====================
template <bool USE_WS>
__global__ void __launch_bounds__(256)
k_dec(const float* __restrict__ x,    const int* __restrict__ pos,
      const float* __restrict__ eps,
      const float* __restrict__ Wd1,  const float* __restrict__ bd1,
      const float* __restrict__ gd1,  const float* __restrict__ bed1,
      const float* __restrict__ Wd2,  const float* __restrict__ bd2,
      const float* __restrict__ gd2,  const float* __restrict__ bed2,
      const float* __restrict__ Wt1,  const float* __restrict__ bt1,
      const float* __restrict__ gt1,  const float* __restrict__ bet1,
      const float* __restrict__ Wt2,  const float* __restrict__ bt2,
      float* __restrict__ out, float* __restrict__ ws)
{
    const int tp = blockIdx.x, tid = threadIdx.x, b = tid;
    const int wid = tid >> 6, lane = tid & 63;

    __shared__ __align__(16) float sWd1[1024];
    __shared__ __align__(16) float sWd2[8192];
    __shared__ __align__(16) float sWt1[4608];   // remapped: [(ky*3+kx)*16+oc]*32+ic
    __shared__ __align__(16) float sWt2[192];    // remapped: [(c*4+dy*2+dx)]*16+ic
    __shared__ float sBd1[64], sBd2[128], sBt1[16], sBt2[3];
    __shared__ float sRed[4][128];
    __shared__ float sM1[64], sS1[64], sE1[64];
    __shared__ float sM2g[128], sS2g[128], sE2g[128];
    __shared__ float sM3[16], sS3[16], sE3[16];

    for (int i = tid; i < 1024; i += 256) sWd1[i] = Wd1[i];
    for (int i = tid; i < 8192; i += 256) sWd2[i] = Wd2[i];
    for (int i = tid; i < 4608; i += 256) {
        const int ic = i / 144, rem = i % 144, oc = rem / 9, k9 = rem % 9;
        sWt1[(k9 * 16 + oc) * 32 + ic] = Wt1[i];
    }
    if (tid < 192) { const int ic = tid / 12, r = tid % 12; sWt2[r * 16 + ic] = Wt2[tid]; }
    if (tid < 64) sBd1[tid] = bd1[tid];
    if (tid < 128) sBd2[tid] = bd2[tid];
    if (tid < 16) sBt1[tid] = bt1[tid];
    if (tid < 3) sBt2[tid] = bt2[tid];
    __syncthreads();

    // ---- z sample + fc1 (16 -> 64) + relu ----
    float z[16];
    {
        const int base = (tp * 256 + b) * 16;
#pragma unroll
        for (int k = 0; k < 16; k++)
            z[k] = fmaf(eps[base + k], out[O_ZS_PRED + base + k], out[O_ZM_PRED + base + k]);
    }
    float h1[64];
#pragma unroll
    for (int j = 0; j < 64; j++) {
        float v = sBd1[j];
#pragma unroll
        for (int k = 0; k < 16; k += 4) {
            const float4 w = *reinterpret_cast<const float4*>(&sWd1[j * 16 + k]);
            v = fmaf(z[k], w.x, fmaf(z[k + 1], w.y, fmaf(z[k + 2], w.z, fmaf(z[k + 3], w.w, v))));
        }
        h1[j] = fmaxf(v, 0.f);
    }
    // BN over batch, 64 ch
#pragma unroll
    for (int j = 0; j < 64; j++) {
        float s = wred(h1[j]), ss = wred(h1[j] * h1[j]);
        if (lane == 0) { sRed[wid][2 * j] = s; sRed[wid][2 * j + 1] = ss; }
    }
    __syncthreads();
    if (tid < 64) {
        const float s  = sRed[0][2 * tid] + sRed[1][2 * tid] + sRed[2][2 * tid] + sRed[3][2 * tid];
        const float ss = sRed[0][2 * tid + 1] + sRed[1][2 * tid + 1] + sRed[2][2 * tid + 1] + sRed[3][2 * tid + 1];
        const float m = s * (1.f / 256.f);
        const float var = fmaf(-m, m, ss * (1.f / 256.f));
        sM1[tid] = m; sS1[tid] = gd1[tid] * rsqrtf(var + 1e-5f); sE1[tid] = bed1[tid];
    }
    __syncthreads();
#pragma unroll
    for (int j = 0; j < 64; j++) h1[j] = fmaf(h1[j] - sM1[j], sS1[j], sE1[j]);

    // ---- pass 1: fc2 in quadrant groups (j = 4*ic + g) + BN; convT1 quadrant g; BN3 stats ----
    float ls[16], lss[16];
#pragma unroll
    for (int i = 0; i < 16; i++) { ls[i] = 0.f; lss[i] = 0.f; }
    const int hbase = (tp * 256 + b) * 256;   // ws: [tp][b][pos(16)][oc(16)]

#pragma unroll 1
    for (int g = 0; g < 4; g++) {
        float h2g[32];
#pragma unroll
        for (int ic = 0; ic < 32; ic++) {
            const int j = 4 * ic + g;
            float v = sBd2[j];
#pragma unroll
            for (int k = 0; k < 64; k += 4) {
                const float4 w = *reinterpret_cast<const float4*>(&sWd2[j * 64 + k]);
                v = fmaf(h1[k], w.x, fmaf(h1[k + 1], w.y, fmaf(h1[k + 2], w.z, fmaf(h1[k + 3], w.w, v))));
            }
            h2g[ic] = fmaxf(v, 0.f);
        }
#pragma unroll
        for (int ic = 0; ic < 32; ic++) {
            float s = wred(h2g[ic]), ss = wred(h2g[ic] * h2g[ic]);
            if (lane == 0) { sRed[wid][2 * ic] = s; sRed[wid][2 * ic + 1] = ss; }
        }
        __syncthreads();
        if (tid < 32) {
            const float s  = sRed[0][2 * tid] + sRed[1][2 * tid] + sRed[2][2 * tid] + sRed[3][2 * tid];
            const float ss = sRed[0][2 * tid + 1] + sRed[1][2 * tid + 1] + sRed[2][2 * tid + 1] + sRed[3][2 * tid + 1];
            const float m = s * (1.f / 256.f);
            const float var = fmaf(-m, m, ss * (1.f / 256.f));
            sM2g[g * 32 + tid] = m;
            sS2g[g * 32 + tid] = gd2[4 * tid + g] * rsqrtf(var + 1e-5f);
            sE2g[g * 32 + tid] = bed2[4 * tid + g];
        }
        __syncthreads();
#pragma unroll
        for (int ic = 0; ic < 32; ic++)
            h2g[ic] = fmaf(h2g[ic] - sM2g[g * 32 + ic], sS2g[g * 32 + ic], sE2g[g * 32 + ic]);

        const int py0 = (g >> 1) * 2, px0 = (g & 1) * 2;
#pragma unroll 1
        for (int dp = 0; dp < 4; dp++) {
            const int py = py0 + (dp >> 1), px = px0 + (dp & 1);
            const int k9 = ((py + 1) % 3) * 3 + ((px + 1) % 3);
            const int pidx = py * 4 + px;
            float hc[16];
#pragma unroll
            for (int oc = 0; oc < 16; oc++) {
                float v = sBt1[oc];
                const float* wrow = &sWt1[(k9 * 16 + oc) * 32];
#pragma unroll
                for (int ic = 0; ic < 32; ic += 4) {
                    const float4 w = *reinterpret_cast<const float4*>(&wrow[ic]);
                    v = fmaf(h2g[ic], w.x, fmaf(h2g[ic + 1], w.y, fmaf(h2g[ic + 2], w.z, fmaf(h2g[ic + 3], w.w, v))));
                }
                v = fmaxf(v, 0.f);
                hc[oc] = v;
                ls[oc] += v; lss[oc] = fmaf(v, v, lss[oc]);
            }
            if (USE_WS) {
#pragma unroll
                for (int oc = 0; oc < 16; oc++) ws[hbase + pidx * 16 + oc] = hc[oc];
            }
        }
    }

    // BN3: per-channel over (b, 4x4) => N = 4096
#pragma unroll
    for (int oc = 0; oc < 16; oc++) {
        float s = wred(ls[oc]), ss = wred(lss[oc]);
        if (lane == 0) { sRed[wid][2 * oc] = s; sRed[wid][2 * oc + 1] = ss; }
    }
    __syncthreads();
    if (tid < 16) {
        const float s  = sRed[0][2 * tid] + sRed[1][2 * tid] + sRed[2][2 * tid] + sRed[3][2 * tid];
        const float ss = sRed[0][2 * tid + 1] + sRed[1][2 * tid + 1] + sRed[2][2 * tid + 1] + sRed[3][2 * tid + 1];
        const float m = s * (1.f / 4096.f);
        const float var = fmaf(-m, m, ss * (1.f / 4096.f));
        sM3[tid] = m; sS3[tid] = gt1[tid] * rsqrtf(var + 1e-5f); sE3[tid] = bet1[tid];
    }
    __syncthreads();

    // ---- pass 2: normalize h3, convT2 (16->3, 2x2, s2) + sigmoid, write x_recon, nll ----
    const int t = 256 + tp;
    const int pr = 3 * pos[(b * 2 + 0) * 288 + t];
    const int pc = 3 * pos[(b * 2 + 1) * 288 + t];
    const float* xb = x + b * 3072;
    const int rbase = O_XREC + (tp * 256 + b) * 192;
    float err = 0.f;

    if (USE_WS) {
#pragma unroll 1
        for (int pidx = 0; pidx < 16; pidx++) {
            const int py = pidx >> 2, px = pidx & 3;
            float hn[16];
#pragma unroll
            for (int oc = 0; oc < 16; oc++)
                hn[oc] = fmaf(ws[hbase + pidx * 16 + oc] - sM3[oc], sS3[oc], sE3[oc]);
#pragma unroll
            for (int c = 0; c < 3; c++)
#pragma unroll
            for (int dy = 0; dy < 2; dy++)
#pragma unroll
            for (int dx = 0; dx < 2; dx++) {
                const float* w = &sWt2[(c * 4 + dy * 2 + dx) * 16];
                float v = sBt2[c];
#pragma unroll
                for (int ic = 0; ic < 16; ic += 4) {
                    const float4 w4 = *reinterpret_cast<const float4*>(&w[ic]);
                    v = fmaf(hn[ic], w4.x, fmaf(hn[ic + 1], w4.y, fmaf(hn[ic + 2], w4.z, fmaf(hn[ic + 3], w4.w, v))));
                }
                v = sigm(v);
                const int oy = 2 * py + dy, ox = 2 * px + dx;
                out[rbase + c * 64 + oy * 8 + ox] = v;
                const float d = v - xb[c * 1024 + (pr + oy) * 32 + (pc + ox)];
                err = fmaf(d, d, err);
            }
        }
    } else {
        // recompute h2g + convT1 (no workspace)
#pragma unroll 1
        for (int g = 0; g < 4; g++) {
            float h2g[32];
#pragma unroll
            for (int ic = 0; ic < 32; ic++) {
                const int j = 4 * ic + g;
                float v = sBd2[j];
#pragma unroll
                for (int k = 0; k < 64; k += 4) {
                    const float4 w = *reinterpret_cast<const float4*>(&sWd2[j * 64 + k]);
                    v = fmaf(h1[k], w.x, fmaf(h1[k + 1], w.y, fmaf(h1[k + 2], w.z, fmaf(h1[k + 3], w.w, v))));
                }
                v = fmaxf(v, 0.f);
                h2g[ic] = fmaf(v - sM2g[g * 32 + ic], sS2g[g * 32 + ic], sE2g[g * 32 + ic]);
            }
            const int py0 = (g >> 1) * 2, px0 = (g & 1) * 2;
#pragma unroll 1
            for (int dp = 0; dp < 4; dp++) {
                const int py = py0 + (dp >> 1), px = px0 + (dp & 1);
                const int k9 = ((py + 1) % 3) * 3 + ((px + 1) % 3);
                float hn[16];
#pragma unroll
                for (int oc = 0; oc < 16; oc++) {
                    float v = sBt1[oc];
                    const float* wrow = &sWt1[(k9 * 16 + oc) * 32];
#pragma unroll
                    for (int ic = 0; ic < 32; ic += 4) {
                        const float4 w = *reinterpret_cast<const float4*>(&wrow[ic]);
                        v = fmaf(h2g[ic], w.x, fmaf(h2g[ic + 1], w.y, fmaf(h2g[ic + 2], w.z, fmaf(h2g[ic + 3], w.w, v))));
                    }
                    v = fmaxf(v, 0.f);
                    hn[oc] = fmaf(v - sM3[oc], sS3[oc], sE3[oc]);
                }
#pragma unroll
                for (int c = 0; c < 3; c++)
#pragma unroll
                for (int dy = 0; dy < 2; dy++)
#pragma unroll
                for (int dx = 0; dx < 2; dx++) {
                    const float* w = &sWt2[(c * 4 + dy * 2 + dx) * 16];
                    float v = sBt2[c];
#pragma unroll
                    for (int ic = 0; ic < 16; ic += 4) {
                        const float4 w4 = *reinterpret_cast<const float4*>(&w[ic]);
                        v = fmaf(hn[ic], w4.x, fmaf(hn[ic + 1], w4.y, fmaf(hn[ic + 2], w4.z, fmaf(hn[ic + 3], w4.w, v))));
                    }
                    v = sigm(v);
                    const int oy = 2 * py + dy, ox = 2 * px + dx;
                    out[rbase + c * 64 + oy * 8 + ox] = v;
                    const float d = v - xb[c * 1024 + (pr + oy) * 32 + (pc + ox)];
                    err = fmaf(d, d, err);
                }
            }
        }
    }

    // nll reduce + atomic
    const float es = wred(err);
    if (lane == 0) sRed[wid][0] = es;
    __syncthreads();
    if (tid == 0)
        atomicAdd(&out[O_NLL], sRed[0][0] + sRed[1][0] + sRed[2][0] + sRed[3][0]);
}

// ==================== host ====================
extern "C" void kernel_launch(void* const* d_in, const int* in_sizes, int n_in,
                              void* d_out, int out_size, void* d_ws, size_t ws_size,
                              hipStream_t stream)
{
    const float* x    = (const float*)d_in[0];
    const float* act  = (const float*)d_in[1];
    const int*   pos  = (const int*)d_in[2];
    const float* s0   = (const float*)d_in[3];
    const float* nobs = (const float*)d_in[4];
    const float* nprd = (const float*)d_in[5];
    const float* eps  = (const float*)d_in[6];
    const float* Wa   = (const float*)d_in[7];
    const float* Ws1  = (const float*)d_in[8];
    const float* bs1  = (const float*)d_in[9];
    const float* Ws2  = (const float*)d_in[10];
    const float* bs2  = (const float*)d_in[11];
    const float* Wc1  = (const float*)d_in[12];
    const float* bc1  = (const float*)d_in[13];
    const float* g1   = (const float*)d_in[14];
    const float* be1  = (const float*)d_in[15];
    const float* Wc2  = (const float*)d_in[16];
    const float* bc2  = (const float*)d_in[17];
    const float* g2   = (const float*)d_in[18];
    const float* be2  = (const float*)d_in[19];
    const float* Wzm  = (const float*)d_in[20];
    const float* bzm  = (const float*)d_in[21];
    const float* Wzs  = (const float*)d_in[22];
    const float* bzs  = (const float*)d_in[23];
    const float* Wd1  = (const float*)d_in[24];
    const float* bd1  = (const float*)d_in[25];
    const float* gd1  = (const float*)d_in[26];
    const float* bed1 = (const float*)d_in[27];
    const float* Wd2  = (const float*)d_in[28];
    const float* bd2  = (const float*)d_in[29];
    const float* gd2  = (const float*)d_in[30];
    const float* bed2 = (const float*)d_in[31];
    const float* Wt1  = (const float*)d_in[32];
    const float* bt1  = (const float*)d_in[33];
    const float* gt1  = (const float*)d_in[34];
    const float* bet1 = (const float*)d_in[35];
    const float* Wt2  = (const float*)d_in[36];
    const float* bt2  = (const float*)d_in[37];
    float* out = (float*)d_out;
    float* ws  = (float*)d_ws;

    k_enc_rec<<<dim3(289), dim3(256), 0, stream>>>(
        x, act, pos, s0, nobs, nprd, Wa, Ws1, bs1, Ws2, bs2,
        Wc1, bc1, g1, be1, Wc2, bc2, g2, be2, Wzm, bzm, Wzs, bzs, out);

    const size_t ws_need = (size_t)NTP * 256 * 256 * sizeof(float);  // 8 MB for convT1 activations
    if (ws_size >= ws_need) {
        k_dec<true><<<dim3(32), dim3(256), 0, stream>>>(
            x, pos, eps, Wd1, bd1, gd1, bed1, Wd2, bd2, gd2, bed2,
            Wt1, bt1, gt1, bet1, Wt2, bt2, out, ws);
    } else {
        k_dec<false><<<dim3(32), dim3(256), 0, stream>>>(
            x, pos, eps, Wd1, bd1, gd1, bed1, Wd2, bd2, gd2, bed2,
            Wt1, bt1, gt1, bet1, Wt2, bt2, out, ws);
    }
}

// Round 2
// 1499.420 us; speedup vs baseline: 1.0689x; 1.0689x over previous
//
#include <hip/hip_runtime.h>
#include <hip/hip_bf16.h>
#include <math.h>

// ---------------- problem constants ----------------
#define NB   256      // batch
#define NT   288      // total timesteps
#define NOBS 256
#define NTP  32

// output offsets (floats)
#define O_ST_OBS   0
#define O_ST_PRED  131072
#define O_ZM_OBS   147456
#define O_ZS_OBS   1196032
#define O_ZM_PRED  2244608
#define O_ZS_PRED  2375680
#define O_XREC     2506752
#define O_NLL      4079616

// workspace offsets (floats)
#define W_U    0          // [288][256][2]  = 147456 floats (dead after k_enc_rec)
#define W_H2N  147456     // [32][4][256][32] = 1048576 floats (normalized h2, grouped by quadrant g)
// total ws usage: 1196032 floats = 4.78 MB

__device__ __forceinline__ float wred(float v) {
    v += __shfl_down(v, 32); v += __shfl_down(v, 16); v += __shfl_down(v, 8);
    v += __shfl_down(v, 4);  v += __shfl_down(v, 2);  v += __shfl_down(v, 1);
    return v;
}
__device__ __forceinline__ float sigm(float x) { return 1.0f / (1.0f + __expf(-x)); }
__device__ __forceinline__ float tanh_f(float x) {
    x = fminf(fmaxf(x, -15.0f), 15.0f);
    float e = __expf(2.0f * x);
    return (e - 1.0f) / (e + 1.0f);
}

// ==================== Kernel 0: precompute U[t][b][2] = act^T . Wa (coalesced in t) ====================
extern "C" __global__ void __launch_bounds__(288)
k_pre(const float* __restrict__ act, const float* __restrict__ Wa, float* __restrict__ ws)
{
    const int b = blockIdx.x;     // 0..255
    const int t = threadIdx.x;    // 0..287
    float u0 = 0.f, u1 = 0.f;
#pragma unroll
    for (int a = 0; a < 5; a++) {
        const float av = act[(b * 5 + a) * 288 + t];
        u0 = fmaf(av, Wa[a], u0);
        u1 = fmaf(av, Wa[5 + a], u1);
    }
    ws[W_U + (t * 256 + b) * 2 + 0] = u0;
    ws[W_U + (t * 256 + b) * 2 + 1] = u1;
}

// ==================== Kernel 1: encoder (blocks 0..287) + recurrence (block 288) ====================
extern "C" __global__ void __launch_bounds__(256)
k_enc_rec(const float* __restrict__ x,
          const int*   __restrict__ pos,  const float* __restrict__ s0,
          const float* __restrict__ nobs, const float* __restrict__ npred,
          const float* __restrict__ Ws1,
          const float* __restrict__ bs1,  const float* __restrict__ Ws2,
          const float* __restrict__ bs2,
          const float* __restrict__ Wc1,  const float* __restrict__ bc1,
          const float* __restrict__ g1,   const float* __restrict__ be1,
          const float* __restrict__ Wc2,  const float* __restrict__ bc2,
          const float* __restrict__ g2,   const float* __restrict__ be2,
          const float* __restrict__ Wzm,  const float* __restrict__ bzm,
          const float* __restrict__ Wzs,  const float* __restrict__ bzs,
          const float* __restrict__ ws,
          float* __restrict__ out)
{
    const int tid = threadIdx.x;

    if (blockIdx.x == 288) {
        // ---------------- state recurrence: thread = batch element ----------------
        const int b = tid;
        float w1[10], w2[10], c1[5], c2_0, c2_1;
#pragma unroll
        for (int i = 0; i < 10; i++) { w1[i] = Ws1[i]; w2[i] = Ws2[i]; }
#pragma unroll
        for (int i = 0; i < 5; i++) c1[i] = bs1[i];
        c2_0 = bs2[0]; c2_1 = bs2[1];

        float sv0 = s0[b * 2 + 0], sv1 = s0[b * 2 + 1];
        ((float2*)(out + O_ST_OBS))[b] = make_float2(sv0, sv1);
        if (b == 0) out[O_NLL] = 0.0f;   // re-zeroed every call (stream-ordered before k_dec2)

        const float2* Up = (const float2*)(ws + W_U);
        const float2* Nobs = (const float2*)nobs;
        const float2* Nprd = (const float2*)npred;

        // software prefetch one step ahead
        float2 u  = Up[256 + b];     // t = 1
        float2 nz = Nobs[b];         // noise_obs[0]

        for (int t = 1; t < 288; t++) {
            float2 u_n = make_float2(0.f, 0.f), nz_n = make_float2(0.f, 0.f);
            if (t < 287) {
                u_n = Up[(t + 1) * 256 + b];
                const float2* np = (t + 1 < 256) ? (Nobs + t * 256 + b)
                                                 : (Nprd + (t - 255) * 256 + b);
                nz_n = *np;
            }

            const float v0 = sv0 + u.x, v1 = sv1 + u.y;
            float h[5];
#pragma unroll
            for (int j = 0; j < 5; j++)
                h[j] = tanh_f(fmaf(v1, w1[j * 2 + 1], fmaf(v0, w1[j * 2 + 0], c1[j])));
            // tree-reduced accumulation (shorter dep chain)
            float a0 = fmaf(h[0], w2[0], fmaf(h[1], w2[1], c2_0));
            float a0b = fmaf(h[2], w2[2], h[3] * w2[3]);
            a0 = fmaf(h[4], w2[4], a0 + a0b);
            float a1 = fmaf(h[0], w2[5], fmaf(h[1], w2[6], c2_1));
            float a1b = fmaf(h[2], w2[7], h[3] * w2[8]);
            a1 = fmaf(h[4], w2[9], a1 + a1b);

            sv0 = fmaf(u.x, sigm(a0), sv0) + nz.x;
            sv1 = fmaf(u.y, sigm(a1), sv1) + nz.y;

            if (t < 256) ((float2*)(out + O_ST_OBS))[t * 256 + b] = make_float2(sv0, sv1);
            else         ((float2*)(out + O_ST_PRED))[(t - 256) * 256 + b] = make_float2(sv0, sv1);

            u = u_n; nz = nz_n;
        }
        return;
    }

    // ---------------- glimpse encoder for t = blockIdx.x, thread = batch element ----------------
    const int t = blockIdx.x;
    __shared__ __align__(16) float sWc1[192];
    __shared__ __align__(16) float sWc2[2048];
    __shared__ __align__(16) float sWzm[512];
    __shared__ __align__(16) float sWzs[512];
    __shared__ float sB1[16], sE1[16], sB2[32], sE2[32], sBzm[16], sBzs[16];
    __shared__ float sRed[4][64];
    __shared__ float sM1[16], sS1[16], sM2[32], sS2[32];

    for (int i = tid; i < 192; i += 256) sWc1[i] = Wc1[i];
    for (int i = tid; i < 2048; i += 256) sWc2[i] = Wc2[i];
    for (int i = tid; i < 512; i += 256) { sWzm[i] = Wzm[i]; sWzs[i] = Wzs[i]; }
    if (tid < 16) { sB1[tid] = bc1[tid]; sE1[tid] = be1[tid]; sBzm[tid] = bzm[tid]; sBzs[tid] = bzs[tid]; }
    if (tid < 32) { sB2[tid] = bc2[tid]; sE2[tid] = be2[tid]; }
    __syncthreads();

    const int b = tid;
    const int wid = tid >> 6, lane = tid & 63;
    const float* xb = x + b * 3072;
    const int pr = 3 * pos[(b * 2 + 0) * 288 + t];
    const int pc = 3 * pos[(b * 2 + 1) * 288 + t];

    // conv1 (3->16, 2x2, s2) + relu + maxpool 2x2 -> pooled[16][2][2]
    float pooled[64];
#pragma unroll
    for (int i = 0; i < 64; i++) pooled[i] = 0.f;   // relu outputs >= 0, so 0-init == true max

#pragma unroll
    for (int py = 0; py < 2; py++)
#pragma unroll
    for (int px = 0; px < 2; px++) {
#pragma unroll 1
        for (int d = 0; d < 4; d++) {
            const int dy = d >> 1, dx = d & 1;
            const int rbase = pr + 4 * py + 2 * dy;
            const int cbase = pc + 4 * px + 2 * dx;
            float in[12];
#pragma unroll
            for (int ic = 0; ic < 3; ic++)
#pragma unroll
            for (int ky = 0; ky < 2; ky++)
#pragma unroll
            for (int kx = 0; kx < 2; kx++)
                in[ic * 4 + ky * 2 + kx] = xb[ic * 1024 + (rbase + ky) * 32 + (cbase + kx)];
#pragma unroll
            for (int oc = 0; oc < 16; oc++) {
                float v = sB1[oc];
#pragma unroll
                for (int q = 0; q < 12; q++) v = fmaf(in[q], sWc1[oc * 12 + q], v);
                v = fmaxf(v, 0.f);
                pooled[oc * 4 + py * 2 + px] = fmaxf(pooled[oc * 4 + py * 2 + px], v);
            }
        }
    }

    // BN1: per-channel stats over (b, 2x2) => N = 1024
#pragma unroll
    for (int oc = 0; oc < 16; oc++) {
        float s = 0.f, ss = 0.f;
#pragma unroll
        for (int q = 0; q < 4; q++) { const float v = pooled[oc * 4 + q]; s += v; ss = fmaf(v, v, ss); }
        s = wred(s); ss = wred(ss);
        if (lane == 0) { sRed[wid][oc * 2] = s; sRed[wid][oc * 2 + 1] = ss; }
    }
    __syncthreads();
    if (tid < 16) {
        const float s  = sRed[0][tid * 2] + sRed[1][tid * 2] + sRed[2][tid * 2] + sRed[3][tid * 2];
        const float ss = sRed[0][tid * 2 + 1] + sRed[1][tid * 2 + 1] + sRed[2][tid * 2 + 1] + sRed[3][tid * 2 + 1];
        const float m = s * (1.f / 1024.f);
        const float var = fmaf(-m, m, ss * (1.f / 1024.f));
        sM1[tid] = m; sS1[tid] = g1[tid] * rsqrtf(var + 1e-5f);
    }
    __syncthreads();
#pragma unroll
    for (int oc = 0; oc < 16; oc++) {
        const float m = sM1[oc], sc = sS1[oc], e = sE1[oc];
#pragma unroll
        for (int q = 0; q < 4; q++) pooled[oc * 4 + q] = fmaf(pooled[oc * 4 + q] - m, sc, e);
    }

    // conv2 (16->32, 2x2 over the 2x2 input) + relu
    float h2v[32];
#pragma unroll
    for (int oc = 0; oc < 32; oc++) {
        float v = sB2[oc];
#pragma unroll
        for (int ic = 0; ic < 16; ic++) {
            const float4 w = *reinterpret_cast<const float4*>(&sWc2[oc * 64 + ic * 4]);
            v = fmaf(pooled[ic * 4 + 0], w.x, v); v = fmaf(pooled[ic * 4 + 1], w.y, v);
            v = fmaf(pooled[ic * 4 + 2], w.z, v); v = fmaf(pooled[ic * 4 + 3], w.w, v);
        }
        h2v[oc] = fmaxf(v, 0.f);
    }

    // BN2: per-channel over b => N = 256
#pragma unroll
    for (int oc = 0; oc < 32; oc++) {
        float s = wred(h2v[oc]), ss = wred(h2v[oc] * h2v[oc]);
        if (lane == 0) { sRed[wid][oc * 2] = s; sRed[wid][oc * 2 + 1] = ss; }
    }
    __syncthreads();
    if (tid < 32) {
        const float s  = sRed[0][tid * 2] + sRed[1][tid * 2] + sRed[2][tid * 2] + sRed[3][tid * 2];
        const float ss = sRed[0][tid * 2 + 1] + sRed[1][tid * 2 + 1] + sRed[2][tid * 2 + 1] + sRed[3][tid * 2 + 1];
        const float m = s * (1.f / 256.f);
        const float var = fmaf(-m, m, ss * (1.f / 256.f));
        sM2[tid] = m; sS2[tid] = g2[tid] * rsqrtf(var + 1e-5f);
    }
    __syncthreads();
#pragma unroll
    for (int oc = 0; oc < 32; oc++) h2v[oc] = fmaf(h2v[oc] - sM2[oc], sS2[oc], sE2[oc]);

    // zm / zs heads (32 -> 16 each)
    const int obase_m = (t < 256) ? (O_ZM_OBS + (t * 256 + b) * 16) : (O_ZM_PRED + ((t - 256) * 256 + b) * 16);
    const int obase_s = (t < 256) ? (O_ZS_OBS + (t * 256 + b) * 16) : (O_ZS_PRED + ((t - 256) * 256 + b) * 16);
#pragma unroll
    for (int k = 0; k < 16; k++) {
        float vm = sBzm[k], vs = sBzs[k];
#pragma unroll
        for (int c = 0; c < 32; c += 4) {
            const float4 wm = *reinterpret_cast<const float4*>(&sWzm[k * 32 + c]);
            const float4 ws4 = *reinterpret_cast<const float4*>(&sWzs[k * 32 + c]);
            vm = fmaf(h2v[c], wm.x, fmaf(h2v[c + 1], wm.y, fmaf(h2v[c + 2], wm.z, fmaf(h2v[c + 3], wm.w, vm))));
            vs = fmaf(h2v[c], ws4.x, fmaf(h2v[c + 1], ws4.y, fmaf(h2v[c + 2], ws4.z, fmaf(h2v[c + 3], ws4.w, vs))));
        }
        out[obase_m + k] = vm;
        out[obase_s + k] = __expf(vs);
    }
}

// ==================== Kernel 2: decoder fc1+BN+fc2+BN -> normalized h2 to ws ====================
extern "C" __global__ void __launch_bounds__(256)
k_dec1(const float* __restrict__ eps,
       const float* __restrict__ Wd1,  const float* __restrict__ bd1,
       const float* __restrict__ gd1,  const float* __restrict__ bed1,
       const float* __restrict__ Wd2,  const float* __restrict__ bd2,
       const float* __restrict__ gd2,  const float* __restrict__ bed2,
       const float* __restrict__ out,  float* __restrict__ ws)
{
    const int tp = blockIdx.x, tid = threadIdx.x, b = tid;
    const int wid = tid >> 6, lane = tid & 63;

    __shared__ __align__(16) float sWd1[1024];
    __shared__ __align__(16) float sWd2[8192];
    __shared__ float sBd1[64], sBd2[128];
    __shared__ float sRed[4][128];
    __shared__ float sM1[64], sS1[64], sE1[64];
    __shared__ float sM2[32], sS2[32], sE2[32];

    for (int i = tid; i < 1024; i += 256) sWd1[i] = Wd1[i];
    for (int i = tid; i < 8192; i += 256) sWd2[i] = Wd2[i];
    if (tid < 64) sBd1[tid] = bd1[tid];
    if (tid < 128) sBd2[tid] = bd2[tid];
    __syncthreads();

    // ---- z sample + fc1 (16 -> 64) + relu ----
    float z[16];
    {
        const int base = (tp * 256 + b) * 16;
#pragma unroll
        for (int k = 0; k < 16; k += 4) {
            const float4 e4 = *reinterpret_cast<const float4*>(&eps[base + k]);
            const float4 s4 = *reinterpret_cast<const float4*>(&out[O_ZS_PRED + base + k]);
            const float4 m4 = *reinterpret_cast<const float4*>(&out[O_ZM_PRED + base + k]);
            z[k + 0] = fmaf(e4.x, s4.x, m4.x); z[k + 1] = fmaf(e4.y, s4.y, m4.y);
            z[k + 2] = fmaf(e4.z, s4.z, m4.z); z[k + 3] = fmaf(e4.w, s4.w, m4.w);
        }
    }
    float h1[64];
#pragma unroll
    for (int j = 0; j < 64; j++) {
        float v = sBd1[j];
#pragma unroll
        for (int k = 0; k < 16; k += 4) {
            const float4 w = *reinterpret_cast<const float4*>(&sWd1[j * 16 + k]);
            v = fmaf(z[k], w.x, fmaf(z[k + 1], w.y, fmaf(z[k + 2], w.z, fmaf(z[k + 3], w.w, v))));
        }
        h1[j] = fmaxf(v, 0.f);
    }
    // BN over batch, 64 ch
#pragma unroll
    for (int j = 0; j < 64; j++) {
        float s = wred(h1[j]), ss = wred(h1[j] * h1[j]);
        if (lane == 0) { sRed[wid][2 * j] = s; sRed[wid][2 * j + 1] = ss; }
    }
    __syncthreads();
    if (tid < 64) {
        const float s  = sRed[0][2 * tid] + sRed[1][2 * tid] + sRed[2][2 * tid] + sRed[3][2 * tid];
        const float ss = sRed[0][2 * tid + 1] + sRed[1][2 * tid + 1] + sRed[2][2 * tid + 1] + sRed[3][2 * tid + 1];
        const float m = s * (1.f / 256.f);
        const float var = fmaf(-m, m, ss * (1.f / 256.f));
        sM1[tid] = m; sS1[tid] = gd1[tid] * rsqrtf(var + 1e-5f); sE1[tid] = bed1[tid];
    }
    __syncthreads();
#pragma unroll
    for (int j = 0; j < 64; j++) h1[j] = fmaf(h1[j] - sM1[j], sS1[j], sE1[j]);

    // ---- fc2 in quadrant groups (j = 4*ic + g) + BN2; write normalized h2 to ws ----
#pragma unroll 1
    for (int g = 0; g < 4; g++) {
        float h2g[32];
#pragma unroll
        for (int ic = 0; ic < 32; ic++) {
            const int j = 4 * ic + g;
            float v = sBd2[j];
#pragma unroll
            for (int k = 0; k < 64; k += 4) {
                const float4 w = *reinterpret_cast<const float4*>(&sWd2[j * 64 + k]);
                v = fmaf(h1[k], w.x, fmaf(h1[k + 1], w.y, fmaf(h1[k + 2], w.z, fmaf(h1[k + 3], w.w, v))));
            }
            h2g[ic] = fmaxf(v, 0.f);
        }
#pragma unroll
        for (int ic = 0; ic < 32; ic++) {
            float s = wred(h2g[ic]), ss = wred(h2g[ic] * h2g[ic]);
            if (lane == 0) { sRed[wid][2 * ic] = s; sRed[wid][2 * ic + 1] = ss; }
        }
        __syncthreads();
        if (tid < 32) {
            const float s  = sRed[0][2 * tid] + sRed[1][2 * tid] + sRed[2][2 * tid] + sRed[3][2 * tid];
            const float ss = sRed[0][2 * tid + 1] + sRed[1][2 * tid + 1] + sRed[2][2 * tid + 1] + sRed[3][2 * tid + 1];
            const float m = s * (1.f / 256.f);
            const float var = fmaf(-m, m, ss * (1.f / 256.f));
            sM2[tid] = m;
            sS2[tid] = gd2[4 * tid + g] * rsqrtf(var + 1e-5f);
            sE2[tid] = bed2[4 * tid + g];
        }
        __syncthreads();
        float* dst = ws + W_H2N + (((tp * 4 + g) * 256 + b) * 32);
#pragma unroll
        for (int ic = 0; ic < 32; ic += 4) {
            float4 o4;
            o4.x = fmaf(h2g[ic + 0] - sM2[ic + 0], sS2[ic + 0], sE2[ic + 0]);
            o4.y = fmaf(h2g[ic + 1] - sM2[ic + 1], sS2[ic + 1], sE2[ic + 1]);
            o4.z = fmaf(h2g[ic + 2] - sM2[ic + 2], sS2[ic + 2], sE2[ic + 2]);
            o4.w = fmaf(h2g[ic + 3] - sM2[ic + 3], sS2[ic + 3], sE2[ic + 3]);
            *reinterpret_cast<float4*>(&dst[ic]) = o4;
        }
        __syncthreads();   // sM2/sS2/sE2 reused next g
    }
}

// ==================== Kernel 3: convT1 + BN3 + convT2 + nll ====================
extern "C" __global__ void __launch_bounds__(256)
k_dec2(const float* __restrict__ x,    const int* __restrict__ pos,
       const float* __restrict__ Wt1,  const float* __restrict__ bt1,
       const float* __restrict__ gt1,  const float* __restrict__ bet1,
       const float* __restrict__ Wt2,  const float* __restrict__ bt2,
       float* __restrict__ out, const float* __restrict__ ws)
{
    const int tp = blockIdx.x, tid = threadIdx.x, b = tid;
    const int wid = tid >> 6, lane = tid & 63;

    __shared__ __align__(16) float sWt1[4608];   // [(ky*3+kx)*16+oc]*32+ic
    __shared__ __align__(16) float sWt2[192];    // [(c*4+dy*2+dx)]*16+ic
    __shared__ float sBt1[16], sBt2[3];
    __shared__ float sRed[4][64];
    __shared__ float sM3[16], sS3[16], sE3[16];

    for (int i = tid; i < 4608; i += 256) {
        const int ic = i / 144, rem = i % 144, oc = rem / 9, k9 = rem % 9;
        sWt1[(k9 * 16 + oc) * 32 + ic] = Wt1[i];
    }
    if (tid < 192) { const int ic = tid / 12, r = tid % 12; sWt2[r * 16 + ic] = Wt2[tid]; }
    if (tid < 16) sBt1[tid] = bt1[tid];
    if (tid < 3) sBt2[tid] = bt2[tid];
    __syncthreads();

    // ---- pass 1: convT1 over all 16 positions, BN3 stats only ----
    float ls[16], lss[16];
#pragma unroll
    for (int i = 0; i < 16; i++) { ls[i] = 0.f; lss[i] = 0.f; }

#pragma unroll 1
    for (int g = 0; g < 4; g++) {
        float h2g[32];
        const float* src = ws + W_H2N + (((tp * 4 + g) * 256 + b) * 32);
#pragma unroll
        for (int ic = 0; ic < 32; ic += 4) {
            const float4 v4 = *reinterpret_cast<const float4*>(&src[ic]);
            h2g[ic] = v4.x; h2g[ic + 1] = v4.y; h2g[ic + 2] = v4.z; h2g[ic + 3] = v4.w;
        }
        const int py0 = (g >> 1) * 2, px0 = (g & 1) * 2;
#pragma unroll 1
        for (int dp = 0; dp < 4; dp++) {
            const int py = py0 + (dp >> 1), px = px0 + (dp & 1);
            const int k9 = ((py + 1) % 3) * 3 + ((px + 1) % 3);
#pragma unroll
            for (int oc = 0; oc < 16; oc++) {
                float v = sBt1[oc];
                const float* wrow = &sWt1[(k9 * 16 + oc) * 32];
#pragma unroll
                for (int ic = 0; ic < 32; ic += 4) {
                    const float4 w = *reinterpret_cast<const float4*>(&wrow[ic]);
                    v = fmaf(h2g[ic], w.x, fmaf(h2g[ic + 1], w.y, fmaf(h2g[ic + 2], w.z, fmaf(h2g[ic + 3], w.w, v))));
                }
                v = fmaxf(v, 0.f);
                ls[oc] += v; lss[oc] = fmaf(v, v, lss[oc]);
            }
        }
    }

    // BN3: per-channel over (b, 4x4) => N = 4096
#pragma unroll
    for (int oc = 0; oc < 16; oc++) {
        float s = wred(ls[oc]), ss = wred(lss[oc]);
        if (lane == 0) { sRed[wid][2 * oc] = s; sRed[wid][2 * oc + 1] = ss; }
    }
    __syncthreads();
    if (tid < 16) {
        const float s  = sRed[0][2 * tid] + sRed[1][2 * tid] + sRed[2][2 * tid] + sRed[3][2 * tid];
        const float ss = sRed[0][2 * tid + 1] + sRed[1][2 * tid + 1] + sRed[2][2 * tid + 1] + sRed[3][2 * tid + 1];
        const float m = s * (1.f / 4096.f);
        const float var = fmaf(-m, m, ss * (1.f / 4096.f));
        sM3[tid] = m; sS3[tid] = gt1[tid] * rsqrtf(var + 1e-5f); sE3[tid] = bet1[tid];
    }
    __syncthreads();

    // ---- pass 2: recompute convT1, normalize, convT2 (16->3, 2x2, s2) + sigmoid + nll ----
    const int t = 256 + tp;
    const int pr = 3 * pos[(b * 2 + 0) * 288 + t];
    const int pc = 3 * pos[(b * 2 + 1) * 288 + t];
    const float* xb = x + b * 3072;
    const int rbase = O_XREC + (tp * 256 + b) * 192;
    float err = 0.f;

#pragma unroll 1
    for (int g = 0; g < 4; g++) {
        float h2g[32];
        const float* src = ws + W_H2N + (((tp * 4 + g) * 256 + b) * 32);
#pragma unroll
        for (int ic = 0; ic < 32; ic += 4) {
            const float4 v4 = *reinterpret_cast<const float4*>(&src[ic]);
            h2g[ic] = v4.x; h2g[ic + 1] = v4.y; h2g[ic + 2] = v4.z; h2g[ic + 3] = v4.w;
        }
        const int py0 = (g >> 1) * 2, px0 = (g & 1) * 2;
#pragma unroll 1
        for (int dp = 0; dp < 4; dp++) {
            const int py = py0 + (dp >> 1), px = px0 + (dp & 1);
            const int k9 = ((py + 1) % 3) * 3 + ((px + 1) % 3);
            float hn[16];
#pragma unroll
            for (int oc = 0; oc < 16; oc++) {
                float v = sBt1[oc];
                const float* wrow = &sWt1[(k9 * 16 + oc) * 32];
#pragma unroll
                for (int ic = 0; ic < 32; ic += 4) {
                    const float4 w = *reinterpret_cast<const float4*>(&wrow[ic]);
                    v = fmaf(h2g[ic], w.x, fmaf(h2g[ic + 1], w.y, fmaf(h2g[ic + 2], w.z, fmaf(h2g[ic + 3], w.w, v))));
                }
                v = fmaxf(v, 0.f);
                hn[oc] = fmaf(v - sM3[oc], sS3[oc], sE3[oc]);
            }
#pragma unroll
            for (int c = 0; c < 3; c++)
#pragma unroll
            for (int dy = 0; dy < 2; dy++)
#pragma unroll
            for (int dx = 0; dx < 2; dx++) {
                const float* w = &sWt2[(c * 4 + dy * 2 + dx) * 16];
                float v = sBt2[c];
#pragma unroll
                for (int ic = 0; ic < 16; ic += 4) {
                    const float4 w4 = *reinterpret_cast<const float4*>(&w[ic]);
                    v = fmaf(hn[ic], w4.x, fmaf(hn[ic + 1], w4.y, fmaf(hn[ic + 2], w4.z, fmaf(hn[ic + 3], w4.w, v))));
                }
                v = sigm(v);
                const int oy = 2 * py + dy, ox = 2 * px + dx;
                out[rbase + c * 64 + oy * 8 + ox] = v;
                const float d = v - xb[c * 1024 + (pr + oy) * 32 + (pc + ox)];
                err = fmaf(d, d, err);
            }
        }
    }

    // nll reduce + atomic
    const float es = wred(err);
    if (lane == 0) sRed[wid][0] = es;
    __syncthreads();
    if (tid == 0)
        atomicAdd(&out[O_NLL], sRed[0][0] + sRed[1][0] + sRed[2][0] + sRed[3][0]);
}

// ==================== host ====================
extern "C" void kernel_launch(void* const* d_in, const int* in_sizes, int n_in,
                              void* d_out, int out_size, void* d_ws, size_t ws_size,
                              hipStream_t stream)
{
    const float* x    = (const float*)d_in[0];
    const float* act  = (const float*)d_in[1];
    const int*   pos  = (const int*)d_in[2];
    const float* s0   = (const float*)d_in[3];
    const float* nobs = (const float*)d_in[4];
    const float* nprd = (const float*)d_in[5];
    const float* eps  = (const float*)d_in[6];
    const float* Wa   = (const float*)d_in[7];
    const float* Ws1  = (const float*)d_in[8];
    const float* bs1  = (const float*)d_in[9];
    const float* Ws2  = (const float*)d_in[10];
    const float* bs2  = (const float*)d_in[11];
    const float* Wc1  = (const float*)d_in[12];
    const float* bc1  = (const float*)d_in[13];
    const float* g1   = (const float*)d_in[14];
    const float* be1  = (const float*)d_in[15];
    const float* Wc2  = (const float*)d_in[16];
    const float* bc2  = (const float*)d_in[17];
    const float* g2   = (const float*)d_in[18];
    const float* be2  = (const float*)d_in[19];
    const float* Wzm  = (const float*)d_in[20];
    const float* bzm  = (const float*)d_in[21];
    const float* Wzs  = (const float*)d_in[22];
    const float* bzs  = (const float*)d_in[23];
    const float* Wd1  = (const float*)d_in[24];
    const float* bd1  = (const float*)d_in[25];
    const float* gd1  = (const float*)d_in[26];
    const float* bed1 = (const float*)d_in[27];
    const float* Wd2  = (const float*)d_in[28];
    const float* bd2  = (const float*)d_in[29];
    const float* gd2  = (const float*)d_in[30];
    const float* bed2 = (const float*)d_in[31];
    const float* Wt1  = (const float*)d_in[32];
    const float* bt1  = (const float*)d_in[33];
    const float* gt1  = (const float*)d_in[34];
    const float* bet1 = (const float*)d_in[35];
    const float* Wt2  = (const float*)d_in[36];
    const float* bt2  = (const float*)d_in[37];
    float* out = (float*)d_out;
    float* ws  = (float*)d_ws;

    k_pre<<<dim3(256), dim3(288), 0, stream>>>(act, Wa, ws);

    k_enc_rec<<<dim3(289), dim3(256), 0, stream>>>(
        x, pos, s0, nobs, nprd, Ws1, bs1, Ws2, bs2,
        Wc1, bc1, g1, be1, Wc2, bc2, g2, be2, Wzm, bzm, Wzs, bzs, ws, out);

    k_dec1<<<dim3(32), dim3(256), 0, stream>>>(
        eps, Wd1, bd1, gd1, bed1, Wd2, bd2, gd2, bed2, out, ws);

    k_dec2<<<dim3(32), dim3(256), 0, stream>>>(
        x, pos, Wt1, bt1, gt1, bet1, Wt2, bt2, out, ws);
}

// Round 4
// 388.773 us; speedup vs baseline: 4.1225x; 3.8568x over previous
//
#include <hip/hip_runtime.h>
#include <hip/hip_bf16.h>
#include <math.h>

// ---------------- problem constants ----------------
#define NB   256
#define NT   288
#define NOBS 256
#define NTP  32

// output offsets (floats)
#define O_ST_OBS   0
#define O_ST_PRED  131072
#define O_ZM_OBS   147456
#define O_ZS_OBS   1196032
#define O_ZM_PRED  2244608
#define O_ZS_PRED  2375680
#define O_XREC     2506752
#define O_NLL      4079616

// workspace offsets (floats)
#define W_U    0          // [288][256][2]
#define W_H2N  147456     // [32][4][256][32] normalized h2 by quadrant
// total ws usage: 4.78 MB (validated in round 2)

__device__ __forceinline__ float wred(float v) {
    v += __shfl_down(v, 32); v += __shfl_down(v, 16); v += __shfl_down(v, 8);
    v += __shfl_down(v, 4);  v += __shfl_down(v, 2);  v += __shfl_down(v, 1);
    return v;
}
__device__ __forceinline__ float sigm(float x) { return 1.0f / (1.0f + __expf(-x)); }
__device__ __forceinline__ float tanh_f(float x) {
    x = fminf(fmaxf(x, -15.0f), 15.0f);
    float e = __expf(2.0f * x);
    return (e - 1.0f) / (e + 1.0f);
}
// NOTE: no macro parameter may be named x/y/z/w (member-access collision!)
#define FMA4(ax,ay,az,aw,wv,acc) fmaf((ax),(wv).x,fmaf((ay),(wv).y,fmaf((az),(wv).z,fmaf((aw),(wv).w,(acc)))))

// ==================== Kernel 0: U[t][b][2] = act^T . Wa ====================
extern "C" __global__ void __launch_bounds__(288)
k_pre(const float* __restrict__ act, const float* __restrict__ Wa, float* __restrict__ ws)
{
    const int b = blockIdx.x;     // 0..255
    const int t = threadIdx.x;    // 0..287
    float u0 = 0.f, u1 = 0.f;
#pragma unroll
    for (int a = 0; a < 5; a++) {
        const float av = act[(b * 5 + a) * 288 + t];
        u0 = fmaf(av, Wa[a], u0);
        u1 = fmaf(av, Wa[5 + a], u1);
    }
    ws[W_U + (t * 256 + b) * 2 + 0] = u0;
    ws[W_U + (t * 256 + b) * 2 + 1] = u1;
}

// ==================== Kernel 1: recurrence (block 0) + encoder (blocks 1..288) ====================
extern "C" __global__ void __launch_bounds__(256)
k_enc_rec(const float* __restrict__ x,
          const int*   __restrict__ pos,  const float* __restrict__ s0,
          const float* __restrict__ nobs, const float* __restrict__ npred,
          const float* __restrict__ Ws1,  const float* __restrict__ bs1,
          const float* __restrict__ Ws2,  const float* __restrict__ bs2,
          const float* __restrict__ Wc1,  const float* __restrict__ bc1,
          const float* __restrict__ g1,   const float* __restrict__ be1,
          const float* __restrict__ Wc2,  const float* __restrict__ bc2,
          const float* __restrict__ g2,   const float* __restrict__ be2,
          const float* __restrict__ Wzm,  const float* __restrict__ bzm,
          const float* __restrict__ Wzs,  const float* __restrict__ bzs,
          const float* __restrict__ ws,
          float* __restrict__ out)
{
    const int tid = threadIdx.x;

    if (blockIdx.x == 0) {
        // ---------------- state recurrence: thread = batch element ----------------
        const int b = tid;
        float w1[10], w2[10], c1[5], c2_0, c2_1;
#pragma unroll
        for (int i = 0; i < 10; i++) { w1[i] = Ws1[i]; w2[i] = Ws2[i]; }
#pragma unroll
        for (int i = 0; i < 5; i++) c1[i] = bs1[i];
        c2_0 = bs2[0]; c2_1 = bs2[1];

        float sv0 = s0[b * 2 + 0], sv1 = s0[b * 2 + 1];
        ((float2*)(out + O_ST_OBS))[b] = make_float2(sv0, sv1);
        if (b == 0) out[O_NLL] = 0.0f;   // re-zeroed every call, stream-ordered before k_dec2

        const float2* Up   = (const float2*)(ws + W_U);
        const float2* Nobs = (const float2*)nobs;
        const float2* Nprd = (const float2*)npred;

        float2 u  = Up[256 + b];
        float2 nz = Nobs[b];

        for (int t = 1; t < 288; t++) {
            float2 u_n = make_float2(0.f, 0.f), nz_n = make_float2(0.f, 0.f);
            if (t < 287) {
                u_n = Up[(t + 1) * 256 + b];
                const float2* np = (t + 1 < 256) ? (Nobs + t * 256 + b)
                                                 : (Nprd + (t - 255) * 256 + b);
                nz_n = *np;
            }
            const float v0 = sv0 + u.x, v1 = sv1 + u.y;
            float h[5];
#pragma unroll
            for (int j = 0; j < 5; j++)
                h[j] = tanh_f(fmaf(v1, w1[j * 2 + 1], fmaf(v0, w1[j * 2 + 0], c1[j])));
            float a0 = fmaf(h[0], w2[0], fmaf(h[1], w2[1], c2_0));
            float a0b = fmaf(h[2], w2[2], h[3] * w2[3]);
            a0 = fmaf(h[4], w2[4], a0 + a0b);
            float a1 = fmaf(h[0], w2[5], fmaf(h[1], w2[6], c2_1));
            float a1b = fmaf(h[2], w2[7], h[3] * w2[8]);
            a1 = fmaf(h[4], w2[9], a1 + a1b);

            sv0 = fmaf(u.x, sigm(a0), sv0) + nz.x;
            sv1 = fmaf(u.y, sigm(a1), sv1) + nz.y;

            if (t < 256) ((float2*)(out + O_ST_OBS))[t * 256 + b] = make_float2(sv0, sv1);
            else         ((float2*)(out + O_ST_PRED))[(t - 256) * 256 + b] = make_float2(sv0, sv1);

            u = u_n; nz = nz_n;
        }
        return;
    }

    // ---------------- glimpse encoder, t = blockIdx.x - 1, thread = batch ----------------
    const int t = blockIdx.x - 1;
    __shared__ __align__(16) float sWc1[192];
    __shared__ __align__(16) float sWc2r[2048];   // remapped [oc][q][ic]
    __shared__ __align__(16) float sWzm[512];
    __shared__ __align__(16) float sWzs[512];
    __shared__ __align__(16) float sM1[16], sS1[16], sE1[16];
    __shared__ float sB1[16], sB2[32], sE2[32], sBzm[16], sBzs[16];
    __shared__ float sM2[32], sS2[32];
    __shared__ float sRed[4][128];
    __shared__ __align__(16) float pooledL[256 * 68];   // row-major [b][pos*16+oc], stride 68

    for (int i = tid; i < 192; i += 256) sWc1[i] = Wc1[i];
    for (int i = tid; i < 2048; i += 256) {
        const int oc = i >> 6, rem = i & 63, ic = rem >> 2, q = rem & 3;
        sWc2r[oc * 64 + q * 16 + ic] = Wc2[i];
    }
    for (int i = tid; i < 512; i += 256) { sWzm[i] = Wzm[i]; sWzs[i] = Wzs[i]; }
    if (tid < 16) { sB1[tid] = bc1[tid]; sE1[tid] = be1[tid]; sBzm[tid] = bzm[tid]; sBzs[tid] = bzs[tid]; }
    if (tid < 32) { sB2[tid] = bc2[tid]; sE2[tid] = be2[tid]; }
    __syncthreads();

    const int b = tid;
    const int wid = tid >> 6, lane = tid & 63;
    const float* xb = x + b * 3072;
    const int pr = 3 * pos[(b * 2 + 0) * 288 + t];
    const int pc = 3 * pos[(b * 2 + 1) * 288 + t];
    float* myrow = &pooledL[b * 68];

    // ---- conv1 (3->16, 2x2, s2) + relu + maxpool -> LDS row [pos*16+oc] ----
#pragma unroll
    for (int py = 0; py < 2; py++)
#pragma unroll
    for (int px = 0; px < 2; px++) {
        float p16[16];
#pragma unroll
        for (int i = 0; i < 16; i++) p16[i] = 0.f;    // relu >= 0
#pragma unroll 2
        for (int d = 0; d < 4; d++) {
            const int rbase = pr + 4 * py + 2 * (d >> 1);
            const int cbase = pc + 4 * px + 2 * (d & 1);
            float in[12];
#pragma unroll
            for (int ic = 0; ic < 3; ic++)
#pragma unroll
            for (int ky = 0; ky < 2; ky++)
#pragma unroll
            for (int kx = 0; kx < 2; kx++)
                in[ic * 4 + ky * 2 + kx] = xb[ic * 1024 + (rbase + ky) * 32 + (cbase + kx)];
#pragma unroll
            for (int oc = 0; oc < 16; oc++) {
                const float4 wq0 = *(const float4*)&sWc1[oc * 12 + 0];
                const float4 wq1 = *(const float4*)&sWc1[oc * 12 + 4];
                const float4 wq2 = *(const float4*)&sWc1[oc * 12 + 8];
                float v = sB1[oc];
                v = FMA4(in[0], in[1], in[2], in[3], wq0, v);
                v = FMA4(in[4], in[5], in[6], in[7], wq1, v);
                v = FMA4(in[8], in[9], in[10], in[11], wq2, v);
                p16[oc] = fmaxf(p16[oc], fmaxf(v, 0.f));
            }
        }
        const int pbase = (py * 2 + px) * 16;
        *(float4*)&myrow[pbase + 0]  = make_float4(p16[0], p16[1], p16[2], p16[3]);
        *(float4*)&myrow[pbase + 4]  = make_float4(p16[4], p16[5], p16[6], p16[7]);
        *(float4*)&myrow[pbase + 8]  = make_float4(p16[8], p16[9], p16[10], p16[11]);
        *(float4*)&myrow[pbase + 12] = make_float4(p16[12], p16[13], p16[14], p16[15]);
    }
    __syncthreads();

    // ---- BN1 stats: per channel over (b, 4 pos) = 1024; column partial sums ----
    {
        const int col = tid & 63, q = tid >> 6;
        float s = 0.f, ss = 0.f;
        const float* cp = &pooledL[(q * 64) * 68 + col];
#pragma unroll 4
        for (int i = 0; i < 64; i++) { const float v = cp[i * 68]; s += v; ss = fmaf(v, v, ss); }
        sRed[q][2 * col] = s; sRed[q][2 * col + 1] = ss;
    }
    __syncthreads();
    if (tid < 16) {
        float s = 0.f, ss = 0.f;
#pragma unroll
        for (int p = 0; p < 4; p++)
#pragma unroll
        for (int q = 0; q < 4; q++) { s += sRed[q][2 * (p * 16 + tid)]; ss += sRed[q][2 * (p * 16 + tid) + 1]; }
        const float m = s * (1.f / 1024.f);
        const float var = fmaf(-m, m, ss * (1.f / 1024.f));
        sM1[tid] = m; sS1[tid] = g1[tid] * rsqrtf(var + 1e-5f);
    }
    __syncthreads();

    // ---- normalize own row (quad tq: pos=tq>>2, ic0=(tq&3)*4) ----
#pragma unroll 4
    for (int tq = 0; tq < 16; tq++) {
        const int ic0 = (tq & 3) * 4;
        float4 v = *(float4*)&myrow[4 * tq];
        const float4 mq = *(const float4*)&sM1[ic0];
        const float4 sq = *(const float4*)&sS1[ic0];
        const float4 eq = *(const float4*)&sE1[ic0];
        v.x = fmaf(v.x - mq.x, sq.x, eq.x);
        v.y = fmaf(v.y - mq.y, sq.y, eq.y);
        v.z = fmaf(v.z - mq.z, sq.z, eq.z);
        v.w = fmaf(v.w - mq.w, sq.w, eq.w);
        *(float4*)&myrow[4 * tq] = v;
    }

    // ---- conv2 (16ch x 4pos -> 32) + relu, register-blocked JB=8 ----
    float h2v[32];
#pragma unroll
    for (int og = 0; og < 4; og++) {
        float acc[8];
#pragma unroll
        for (int jj = 0; jj < 8; jj++) acc[jj] = sB2[og * 8 + jj];
#pragma unroll 2
        for (int tq = 0; tq < 16; tq++) {
            const float4 hq = *(const float4*)&myrow[4 * tq];
#pragma unroll
            for (int jj = 0; jj < 8; jj++) {
                const float4 wv = *(const float4*)&sWc2r[(og * 8 + jj) * 64 + 4 * tq];
                acc[jj] = FMA4(hq.x, hq.y, hq.z, hq.w, wv, acc[jj]);
            }
        }
#pragma unroll
        for (int jj = 0; jj < 8; jj++) h2v[og * 8 + jj] = fmaxf(acc[jj], 0.f);
    }

    // ---- BN2: per-channel over b (wred; h2v static-indexed regs) ----
#pragma unroll
    for (int oc = 0; oc < 32; oc++) {
        float s = wred(h2v[oc]), ss = wred(h2v[oc] * h2v[oc]);
        if (lane == 0) { sRed[wid][2 * oc] = s; sRed[wid][2 * oc + 1] = ss; }
    }
    __syncthreads();
    if (tid < 32) {
        const float s  = sRed[0][2 * tid] + sRed[1][2 * tid] + sRed[2][2 * tid] + sRed[3][2 * tid];
        const float ss = sRed[0][2 * tid + 1] + sRed[1][2 * tid + 1] + sRed[2][2 * tid + 1] + sRed[3][2 * tid + 1];
        const float m = s * (1.f / 256.f);
        const float var = fmaf(-m, m, ss * (1.f / 256.f));
        sM2[tid] = m; sS2[tid] = g2[tid] * rsqrtf(var + 1e-5f);
    }
    __syncthreads();
#pragma unroll
    for (int oc = 0; oc < 32; oc++) h2v[oc] = fmaf(h2v[oc] - sM2[oc], sS2[oc], sE2[oc]);

    // ---- zm / zs heads (32 -> 16 each) ----
    const int obase_m = (t < 256) ? (O_ZM_OBS + (t * 256 + b) * 16) : (O_ZM_PRED + ((t - 256) * 256 + b) * 16);
    const int obase_s = (t < 256) ? (O_ZS_OBS + (t * 256 + b) * 16) : (O_ZS_PRED + ((t - 256) * 256 + b) * 16);
#pragma unroll 2
    for (int k = 0; k < 16; k++) {
        float vm = sBzm[k], vs = sBzs[k];
#pragma unroll
        for (int c = 0; c < 32; c += 4) {
            const float4 wm = *(const float4*)&sWzm[k * 32 + c];
            const float4 wsq = *(const float4*)&sWzs[k * 32 + c];
            vm = FMA4(h2v[c], h2v[c + 1], h2v[c + 2], h2v[c + 3], wm, vm);
            vs = FMA4(h2v[c], h2v[c + 1], h2v[c + 2], h2v[c + 3], wsq, vs);
        }
        out[obase_m + k] = vm;
        out[obase_s + k] = __expf(vs);
    }
}

// ==================== Kernel 2: z + fc1 + BN + fc2 + BN -> ws (h1 staged in LDS) ====================
extern "C" __global__ void __launch_bounds__(256)
k_dec1(const float* __restrict__ eps,
       const float* __restrict__ Wd1,  const float* __restrict__ bd1,
       const float* __restrict__ gd1,  const float* __restrict__ bed1,
       const float* __restrict__ Wd2,  const float* __restrict__ bd2,
       const float* __restrict__ gd2,  const float* __restrict__ bed2,
       const float* __restrict__ out,  float* __restrict__ ws)
{
    const int tp = blockIdx.x, tid = threadIdx.x, b = tid;
    const int wid = tid >> 6, lane = tid & 63;

    __shared__ __align__(16) float sWd1[1024];
    __shared__ __align__(16) float sWd2[8192];
    __shared__ __align__(16) float h1L[256 * 68];    // row-major [b][64ch], stride 68
    __shared__ __align__(16) float sM1[64], sS1[64], sE1[64];
    __shared__ float sBd1[64], sBd2[128];
    __shared__ float sRed[4][128];
    __shared__ float sM2[32], sS2[32], sE2[32];

    for (int i = tid; i < 1024; i += 256) sWd1[i] = Wd1[i];
    for (int i = tid; i < 8192; i += 256) sWd2[i] = Wd2[i];
    if (tid < 64) sBd1[tid] = bd1[tid];
    if (tid < 128) sBd2[tid] = bd2[tid];
    __syncthreads();

    // ---- z sample (4 named quads, static) ----
    float4 zA, zB, zC, zD;
    {
        const int base = (tp * 256 + b) * 16;
        const float4 e0 = *(const float4*)&eps[base + 0],  e1 = *(const float4*)&eps[base + 4];
        const float4 e2 = *(const float4*)&eps[base + 8],  e3 = *(const float4*)&eps[base + 12];
        const float4 s0 = *(const float4*)&out[O_ZS_PRED + base + 0],  s1 = *(const float4*)&out[O_ZS_PRED + base + 4];
        const float4 s2 = *(const float4*)&out[O_ZS_PRED + base + 8],  s3 = *(const float4*)&out[O_ZS_PRED + base + 12];
        const float4 m0 = *(const float4*)&out[O_ZM_PRED + base + 0],  m1 = *(const float4*)&out[O_ZM_PRED + base + 4];
        const float4 m2 = *(const float4*)&out[O_ZM_PRED + base + 8],  m3 = *(const float4*)&out[O_ZM_PRED + base + 12];
        zA = make_float4(fmaf(e0.x,s0.x,m0.x), fmaf(e0.y,s0.y,m0.y), fmaf(e0.z,s0.z,m0.z), fmaf(e0.w,s0.w,m0.w));
        zB = make_float4(fmaf(e1.x,s1.x,m1.x), fmaf(e1.y,s1.y,m1.y), fmaf(e1.z,s1.z,m1.z), fmaf(e1.w,s1.w,m1.w));
        zC = make_float4(fmaf(e2.x,s2.x,m2.x), fmaf(e2.y,s2.y,m2.y), fmaf(e2.z,s2.z,m2.z), fmaf(e2.w,s2.w,m2.w));
        zD = make_float4(fmaf(e3.x,s3.x,m3.x), fmaf(e3.y,s3.y,m3.y), fmaf(e3.z,s3.z,m3.z), fmaf(e3.w,s3.w,m3.w));
    }

    // ---- fc1 (16->64) + relu -> LDS row ----
    float* myrow = &h1L[b * 68];
#pragma unroll 1
    for (int jg = 0; jg < 8; jg++) {
        const int j0 = jg * 8;
        float acc[8];
#pragma unroll
        for (int jj = 0; jj < 8; jj++) {
            const float4 wq0 = *(const float4*)&sWd1[(j0 + jj) * 16 + 0];
            const float4 wq1 = *(const float4*)&sWd1[(j0 + jj) * 16 + 4];
            const float4 wq2 = *(const float4*)&sWd1[(j0 + jj) * 16 + 8];
            const float4 wq3 = *(const float4*)&sWd1[(j0 + jj) * 16 + 12];
            float v = sBd1[j0 + jj];
            v = FMA4(zA.x, zA.y, zA.z, zA.w, wq0, v);
            v = FMA4(zB.x, zB.y, zB.z, zB.w, wq1, v);
            v = FMA4(zC.x, zC.y, zC.z, zC.w, wq2, v);
            v = FMA4(zD.x, zD.y, zD.z, zD.w, wq3, v);
            acc[jj] = fmaxf(v, 0.f);
        }
        *(float4*)&myrow[j0 + 0] = make_float4(acc[0], acc[1], acc[2], acc[3]);
        *(float4*)&myrow[j0 + 4] = make_float4(acc[4], acc[5], acc[6], acc[7]);
    }
    __syncthreads();

    // ---- BN1 stats: per channel j over b, column partial sums ----
    {
        const int j = tid & 63, q = tid >> 6;
        float s = 0.f, ss = 0.f;
        const float* cp = &h1L[(q * 64) * 68 + j];
#pragma unroll 4
        for (int i = 0; i < 64; i++) { const float v = cp[i * 68]; s += v; ss = fmaf(v, v, ss); }
        sRed[q][2 * j] = s; sRed[q][2 * j + 1] = ss;
    }
    __syncthreads();
    if (tid < 64) {
        const float s  = sRed[0][2 * tid] + sRed[1][2 * tid] + sRed[2][2 * tid] + sRed[3][2 * tid];
        const float ss = sRed[0][2 * tid + 1] + sRed[1][2 * tid + 1] + sRed[2][2 * tid + 1] + sRed[3][2 * tid + 1];
        const float m = s * (1.f / 256.f);
        const float var = fmaf(-m, m, ss * (1.f / 256.f));
        sM1[tid] = m; sS1[tid] = gd1[tid] * rsqrtf(var + 1e-5f); sE1[tid] = bed1[tid];
    }
    __syncthreads();

    // ---- normalize own row ----
#pragma unroll 4
    for (int k4 = 0; k4 < 16; k4++) {
        float4 v = *(float4*)&myrow[4 * k4];
        const float4 mq = *(const float4*)&sM1[4 * k4];
        const float4 sq = *(const float4*)&sS1[4 * k4];
        const float4 eq = *(const float4*)&sE1[4 * k4];
        v.x = fmaf(v.x - mq.x, sq.x, eq.x);
        v.y = fmaf(v.y - mq.y, sq.y, eq.y);
        v.z = fmaf(v.z - mq.z, sq.z, eq.z);
        v.w = fmaf(v.w - mq.w, sq.w, eq.w);
        *(float4*)&myrow[4 * k4] = v;
    }

    // ---- fc2 (64->128) per quadrant g (j = 4*ic+g) + BN2, write to ws ----
#pragma unroll 1
    for (int g = 0; g < 4; g++) {
        float h2g[32];
#pragma unroll
        for (int icg = 0; icg < 4; icg++) {
            const int ic0 = icg * 8;
            float acc[8];
#pragma unroll
            for (int jj = 0; jj < 8; jj++) acc[jj] = sBd2[4 * (ic0 + jj) + g];
#pragma unroll 1
            for (int k4 = 0; k4 < 16; k4++) {
                const float4 hq = *(const float4*)&myrow[4 * k4];
#pragma unroll
                for (int jj = 0; jj < 8; jj++) {
                    const float4 wv = *(const float4*)&sWd2[(4 * (ic0 + jj) + g) * 64 + 4 * k4];
                    acc[jj] = FMA4(hq.x, hq.y, hq.z, hq.w, wv, acc[jj]);
                }
            }
#pragma unroll
            for (int jj = 0; jj < 8; jj++) h2g[ic0 + jj] = fmaxf(acc[jj], 0.f);
        }
        // BN2 stats (wred over regs)
#pragma unroll
        for (int ic = 0; ic < 32; ic++) {
            float s = wred(h2g[ic]), ss = wred(h2g[ic] * h2g[ic]);
            if (lane == 0) { sRed[wid][2 * ic] = s; sRed[wid][2 * ic + 1] = ss; }
        }
        __syncthreads();
        if (tid < 32) {
            const float s  = sRed[0][2 * tid] + sRed[1][2 * tid] + sRed[2][2 * tid] + sRed[3][2 * tid];
            const float ss = sRed[0][2 * tid + 1] + sRed[1][2 * tid + 1] + sRed[2][2 * tid + 1] + sRed[3][2 * tid + 1];
            const float m = s * (1.f / 256.f);
            const float var = fmaf(-m, m, ss * (1.f / 256.f));
            sM2[tid] = m;
            sS2[tid] = gd2[4 * tid + g] * rsqrtf(var + 1e-5f);
            sE2[tid] = bed2[4 * tid + g];
        }
        __syncthreads();
        float* dst = ws + W_H2N + (((tp * 4 + g) * 256 + b) * 32);
#pragma unroll
        for (int ic = 0; ic < 32; ic += 4) {
            float4 o4;
            o4.x = fmaf(h2g[ic + 0] - sM2[ic + 0], sS2[ic + 0], sE2[ic + 0]);
            o4.y = fmaf(h2g[ic + 1] - sM2[ic + 1], sS2[ic + 1], sE2[ic + 1]);
            o4.z = fmaf(h2g[ic + 2] - sM2[ic + 2], sS2[ic + 2], sE2[ic + 2]);
            o4.w = fmaf(h2g[ic + 3] - sM2[ic + 3], sS2[ic + 3], sE2[ic + 3]);
            *(float4*)&dst[ic] = o4;
        }
        __syncthreads();
    }
}

// ==================== Kernel 3: convT1 + BN3 + convT2 + nll ====================
extern "C" __global__ void __launch_bounds__(256)
k_dec2(const float* __restrict__ x,    const int* __restrict__ pos,
       const float* __restrict__ Wt1,  const float* __restrict__ bt1,
       const float* __restrict__ gt1,  const float* __restrict__ bet1,
       const float* __restrict__ Wt2,  const float* __restrict__ bt2,
       float* __restrict__ out, const float* __restrict__ ws)
{
    const int tp = blockIdx.x, tid = threadIdx.x, b = tid;
    const int wid = tid >> 6, lane = tid & 63;

    __shared__ __align__(16) float sWt1[4608];   // [(k9*16+oc)*32+ic]
    __shared__ __align__(16) float sWt2[192];    // [(c*4+dy*2+dx)*16+ic]
    __shared__ float sBt1[16], sBt2[3];
    __shared__ float sRed[4][64];
    __shared__ float sM3[16], sS3[16], sE3[16];

    for (int i = tid; i < 4608; i += 256) {
        const int ic = i / 144, rem = i % 144, oc = rem / 9, k9 = rem % 9;
        sWt1[(k9 * 16 + oc) * 32 + ic] = Wt1[i];
    }
    if (tid < 192) { const int ic = tid / 12, r = tid % 12; sWt2[r * 16 + ic] = Wt2[tid]; }
    if (tid < 16) sBt1[tid] = bt1[tid];
    if (tid < 3) sBt2[tid] = bt2[tid];
    __syncthreads();

    // ---- pass 1: convT1 all 16 positions, BN3 stats ----
    float ls[16], lss[16];
#pragma unroll
    for (int i = 0; i < 16; i++) { ls[i] = 0.f; lss[i] = 0.f; }

#pragma unroll 1
    for (int g = 0; g < 4; g++) {
        float h2g[32];
        const float* src = ws + W_H2N + (((tp * 4 + g) * 256 + b) * 32);
#pragma unroll
        for (int i4 = 0; i4 < 8; i4++) {
            const float4 v4 = *(const float4*)&src[4 * i4];
            h2g[4 * i4] = v4.x; h2g[4 * i4 + 1] = v4.y; h2g[4 * i4 + 2] = v4.z; h2g[4 * i4 + 3] = v4.w;
        }
        const int py0 = (g >> 1) * 2, px0 = (g & 1) * 2;
#pragma unroll 1
        for (int dp = 0; dp < 4; dp++) {
            const int py = py0 + (dp >> 1), px = px0 + (dp & 1);
            const int k9 = ((py + 1) % 3) * 3 + ((px + 1) % 3);
#pragma unroll
            for (int og = 0; og < 4; og++) {
                float acc[4];
#pragma unroll
                for (int jj = 0; jj < 4; jj++) acc[jj] = sBt1[og * 4 + jj];
#pragma unroll
                for (int i4 = 0; i4 < 8; i4++) {
#pragma unroll
                    for (int jj = 0; jj < 4; jj++) {
                        const float4 wv = *(const float4*)&sWt1[(k9 * 16 + og * 4 + jj) * 32 + 4 * i4];
                        acc[jj] = FMA4(h2g[4*i4], h2g[4*i4+1], h2g[4*i4+2], h2g[4*i4+3], wv, acc[jj]);
                    }
                }
#pragma unroll
                for (int jj = 0; jj < 4; jj++) {
                    const float v = fmaxf(acc[jj], 0.f);
                    ls[og * 4 + jj] += v; lss[og * 4 + jj] = fmaf(v, v, lss[og * 4 + jj]);
                }
            }
        }
    }

    // BN3: per-channel over (b, 16 pos) => N = 4096
#pragma unroll
    for (int oc = 0; oc < 16; oc++) {
        float s = wred(ls[oc]), ss = wred(lss[oc]);
        if (lane == 0) { sRed[wid][2 * oc] = s; sRed[wid][2 * oc + 1] = ss; }
    }
    __syncthreads();
    if (tid < 16) {
        const float s  = sRed[0][2 * tid] + sRed[1][2 * tid] + sRed[2][2 * tid] + sRed[3][2 * tid];
        const float ss = sRed[0][2 * tid + 1] + sRed[1][2 * tid + 1] + sRed[2][2 * tid + 1] + sRed[3][2 * tid + 1];
        const float m = s * (1.f / 4096.f);
        const float var = fmaf(-m, m, ss * (1.f / 4096.f));
        sM3[tid] = m; sS3[tid] = gt1[tid] * rsqrtf(var + 1e-5f); sE3[tid] = bet1[tid];
    }
    __syncthreads();

    // ---- pass 2: recompute convT1, normalize, convT2 + sigmoid + nll ----
    const int t = 256 + tp;
    const int pr = 3 * pos[(b * 2 + 0) * 288 + t];
    const int pc = 3 * pos[(b * 2 + 1) * 288 + t];
    const float* xb = x + b * 3072;
    const int rbase = O_XREC + (tp * 256 + b) * 192;
    float err = 0.f;

#pragma unroll 1
    for (int g = 0; g < 4; g++) {
        float h2g[32];
        const float* src = ws + W_H2N + (((tp * 4 + g) * 256 + b) * 32);
#pragma unroll
        for (int i4 = 0; i4 < 8; i4++) {
            const float4 v4 = *(const float4*)&src[4 * i4];
            h2g[4 * i4] = v4.x; h2g[4 * i4 + 1] = v4.y; h2g[4 * i4 + 2] = v4.z; h2g[4 * i4 + 3] = v4.w;
        }
        const int py0 = (g >> 1) * 2, px0 = (g & 1) * 2;
#pragma unroll 1
        for (int dp = 0; dp < 4; dp++) {
            const int py = py0 + (dp >> 1), px = px0 + (dp & 1);
            const int k9 = ((py + 1) % 3) * 3 + ((px + 1) % 3);
            float hn[16];
#pragma unroll
            for (int og = 0; og < 4; og++) {
                float acc[4];
#pragma unroll
                for (int jj = 0; jj < 4; jj++) acc[jj] = sBt1[og * 4 + jj];
#pragma unroll
                for (int i4 = 0; i4 < 8; i4++) {
#pragma unroll
                    for (int jj = 0; jj < 4; jj++) {
                        const float4 wv = *(const float4*)&sWt1[(k9 * 16 + og * 4 + jj) * 32 + 4 * i4];
                        acc[jj] = FMA4(h2g[4*i4], h2g[4*i4+1], h2g[4*i4+2], h2g[4*i4+3], wv, acc[jj]);
                    }
                }
#pragma unroll
                for (int jj = 0; jj < 4; jj++) {
                    const int oc = og * 4 + jj;
                    hn[oc] = fmaf(fmaxf(acc[jj], 0.f) - sM3[oc], sS3[oc], sE3[oc]);
                }
            }
#pragma unroll
            for (int c = 0; c < 3; c++)
#pragma unroll
            for (int dy = 0; dy < 2; dy++)
#pragma unroll
            for (int dx = 0; dx < 2; dx++) {
                const float* wp = &sWt2[(c * 4 + dy * 2 + dx) * 16];
                float v = sBt2[c];
#pragma unroll
                for (int ic = 0; ic < 16; ic += 4) {
                    const float4 wq = *(const float4*)&wp[ic];
                    v = FMA4(hn[ic], hn[ic + 1], hn[ic + 2], hn[ic + 3], wq, v);
                }
                v = sigm(v);
                const int oy = 2 * py + dy, ox = 2 * px + dx;
                out[rbase + c * 64 + oy * 8 + ox] = v;
                const float d = v - xb[c * 1024 + (pr + oy) * 32 + (pc + ox)];
                err = fmaf(d, d, err);
            }
        }
    }

    const float es = wred(err);
    if (lane == 0) sRed[wid][0] = es;
    __syncthreads();
    if (tid == 0)
        atomicAdd(&out[O_NLL], sRed[0][0] + sRed[1][0] + sRed[2][0] + sRed[3][0]);
}

// ==================== host ====================
extern "C" void kernel_launch(void* const* d_in, const int* in_sizes, int n_in,
                              void* d_out, int out_size, void* d_ws, size_t ws_size,
                              hipStream_t stream)
{
    const float* x    = (const float*)d_in[0];
    const float* act  = (const float*)d_in[1];
    const int*   pos  = (const int*)d_in[2];
    const float* s0   = (const float*)d_in[3];
    const float* nobs = (const float*)d_in[4];
    const float* nprd = (const float*)d_in[5];
    const float* eps  = (const float*)d_in[6];
    const float* Wa   = (const float*)d_in[7];
    const float* Ws1  = (const float*)d_in[8];
    const float* bs1  = (const float*)d_in[9];
    const float* Ws2  = (const float*)d_in[10];
    const float* bs2  = (const float*)d_in[11];
    const float* Wc1  = (const float*)d_in[12];
    const float* bc1  = (const float*)d_in[13];
    const float* g1   = (const float*)d_in[14];
    const float* be1  = (const float*)d_in[15];
    const float* Wc2  = (const float*)d_in[16];
    const float* bc2  = (const float*)d_in[17];
    const float* g2   = (const float*)d_in[18];
    const float* be2  = (const float*)d_in[19];
    const float* Wzm  = (const float*)d_in[20];
    const float* bzm  = (const float*)d_in[21];
    const float* Wzs  = (const float*)d_in[22];
    const float* bzs  = (const float*)d_in[23];
    const float* Wd1  = (const float*)d_in[24];
    const float* bd1  = (const float*)d_in[25];
    const float* gd1  = (const float*)d_in[26];
    const float* bed1 = (const float*)d_in[27];
    const float* Wd2  = (const float*)d_in[28];
    const float* bd2  = (const float*)d_in[29];
    const float* gd2  = (const float*)d_in[30];
    const float* bed2 = (const float*)d_in[31];
    const float* Wt1  = (const float*)d_in[32];
    const float* bt1  = (const float*)d_in[33];
    const float* gt1  = (const float*)d_in[34];
    const float* bet1 = (const float*)d_in[35];
    const float* Wt2  = (const float*)d_in[36];
    const float* bt2  = (const float*)d_in[37];
    float* out = (float*)d_out;
    float* ws  = (float*)d_ws;

    k_pre<<<dim3(256), dim3(288), 0, stream>>>(act, Wa, ws);

    k_enc_rec<<<dim3(289), dim3(256), 0, stream>>>(
        x, pos, s0, nobs, nprd, Ws1, bs1, Ws2, bs2,
        Wc1, bc1, g1, be1, Wc2, bc2, g2, be2, Wzm, bzm, Wzs, bzs, ws, out);

    k_dec1<<<dim3(32), dim3(256), 0, stream>>>(
        eps, Wd1, bd1, gd1, bed1, Wd2, bd2, gd2, bed2, out, ws);

    k_dec2<<<dim3(32), dim3(256), 0, stream>>>(
        x, pos, Wt1, bt1, gt1, bet1, Wt2, bt2, out, ws);
}